// Round 16
// baseline (400.738 us; speedup 1.0000x reference)
//
#include <hip/hip_runtime.h>

using bf16x8 = __attribute__((ext_vector_type(8))) __bf16;
using f32x4  = __attribute__((ext_vector_type(4))) float;

#define AS1 __attribute__((address_space(1)))
#define AS3 __attribute__((address_space(3)))

#define SB()     __builtin_amdgcn_s_barrier()
#define SCHED0() __builtin_amdgcn_sched_barrier(0)
#define LGKM0()  asm volatile("s_waitcnt lgkmcnt(0)")
#define VM6()    asm volatile("s_waitcnt vmcnt(6)")
#define VM0()    asm volatile("s_waitcnt vmcnt(0)")

__device__ __forceinline__ unsigned short f2bf(float f) {
    unsigned int x = __float_as_uint(f);
    x += 0x7fffu + ((x >> 16) & 1u);   // RNE
    return (unsigned short)(x >> 16);
}

// bijective XCD-aware block remap (m204)
__device__ __forceinline__ int xcd_remap(int orig, int nwg) {
    int q = nwg >> 3, r = nwg & 7;
    int xcd = orig & 7, lin = orig >> 3;
    return (xcd < r ? xcd * (q + 1) : r * (q + 1) + (xcd - r) * q) + lin;
}

// ---- fused prep: Wqkv^T (1728) | Wproj^T (576) | x cvt (2048) | zero S/qn2/kn2 (294) ----
__global__ __launch_bounds__(256)
void prep_kernel(const float* __restrict__ x, ushort4* __restrict__ xbf,
                 const float* __restrict__ Wqkv, unsigned short* __restrict__ wqkvt,
                 const float* __restrict__ Wproj, unsigned short* __restrict__ wprojt,
                 float4* __restrict__ zbase) {
    __shared__ float tile[32][33];
    int bid = blockIdx.x, tid = threadIdx.x;
    if (bid < 2304) {
        const float* W; unsigned short* Wt; int K = 768, N; int bx, by;
        if (bid < 1728) { W = Wqkv; Wt = wqkvt; N = 2304; bx = bid % 72; by = bid / 72; }
        else            { int t = bid - 1728; W = Wproj; Wt = wprojt; N = 768; bx = t % 24; by = t / 24; }
        int n0 = bx << 5, k0 = by << 5;
        int tx = tid & 31, ty = tid >> 5;      // 32 x 8
#pragma unroll
        for (int i = 0; i < 32; i += 8)
            tile[ty + i][tx] = W[(size_t)(k0 + ty + i) * N + (n0 + tx)];
        __syncthreads();
#pragma unroll
        for (int i = 0; i < 32; i += 8)
            Wt[(size_t)(n0 + ty + i) * K + (k0 + tx)] = f2bf(tile[tx][ty + i]);
    } else if (bid < 4352) {
        int vb = bid - 2304;
        const float4* in = (const float4*)x;
        int n4 = 38535168 / 4;
        int stride = 2048 * 256;
        for (int i = vb * 256 + tid; i < n4; i += stride) {
            float4 v = in[i];
            ushort4 o;
            o.x = f2bf(v.x); o.y = f2bf(v.y); o.z = f2bf(v.z); o.w = f2bf(v.w);
            xbf[i] = o;
        }
    } else {
        int z = bid - 4352;
        float4 zz4 = {0.f, 0.f, 0.f, 0.f};
        for (int i = z * 256 + tid; i < 301056; i += 294 * 256) zbase[i] = zz4;
    }
}

// ============ 256x256 8-phase half-tile-ring GEMM (m201-faithful reconstruction) ============
// 8 waves (2M x 4N), per-wave C 128x64 (acc[8][4]), BK=64, 2 K-tiles/iteration.
// LDS 128KB: [buf][A|B][half] 16KB regions. A-half h = rows {wm*128+h*64 .. +63} packed
// [wm*64 + r]; B-half h = Bt rows {wn*64+h*32 ..} packed [wn*32 + n]. One half-tile
// (2 global_load_lds/thread) staged per phase, targeting the region freed in the PREVIOUS
// phase (BARRIER-B guarantees all waves' reads done). vmcnt(6) only at phases 4/8:
// 3 half-tiles (6 loads) stay in flight across barriers. Proven (row&7)<<4 XOR swizzle.
__device__ __forceinline__ void stA8(const char* Asrc, int ldaB, int Mcap, int h,
                                     char* dst, int tid) {
#pragma unroll
    for (int r = 0; r < 2; ++r) {
        int i = (r << 9) + tid;
        int rho = i >> 3, s = i & 7;
        int grow = ((rho >> 6) << 7) + (h << 6) + (rho & 63);
        if (grow >= Mcap) grow = Mcap - 1;
        __builtin_amdgcn_global_load_lds(
            (AS1 unsigned int*)(unsigned long long)(Asrc + (size_t)grow * ldaB + ((s ^ (rho & 7)) << 4)),
            (AS3 unsigned int*)(dst + (i << 4)), 16, 0, 0);
    }
}
__device__ __forceinline__ void stB8(const char* Bsrc, int ldbB, int h, char* dst, int tid) {
#pragma unroll
    for (int r = 0; r < 2; ++r) {
        int i = (r << 9) + tid;
        int rho = i >> 3, s = i & 7;
        int grow = ((rho >> 5) << 6) + (h << 5) + (rho & 31);
        __builtin_amdgcn_global_lds:
        __builtin_amdgcn_global_load_lds(
            (AS1 unsigned int*)(unsigned long long)(Bsrc + (size_t)grow * ldbB + ((s ^ (rho & 7)) << 4)),
            (AS3 unsigned int*)(dst + (i << 4)), 16, 0, 0);
    }
}

__device__ __forceinline__ bf16x8 rdA8(const char* smem, int buf, int rh, int wm,
                                       int f, int ks, int lane) {
    int rho = (wm << 6) + (f << 4) + (lane & 15);
    int kb = ((ks << 2) + (lane >> 4)) << 4;
    return *(const bf16x8*)(smem + (buf << 16) + (rh << 14) + rho * 128 + (kb ^ ((rho & 7) << 4)));
}
__device__ __forceinline__ bf16x8 rdB8(const char* smem, int buf, int ch, int wn,
                                       int g, int ks, int lane) {
    int rho = (wn << 5) + (g << 4) + (lane & 15);
    int kb = ((ks << 2) + (lane >> 4)) << 4;
    return *(const bf16x8*)(smem + (buf << 16) + 32768 + (ch << 14) + rho * 128 + (kb ^ ((rho & 7) << 4)));
}

#define CL16(MB, CB, BREG)                                                     \
    __builtin_amdgcn_s_setprio(1);                                             \
    _Pragma("unroll") for (int f_ = 0; f_ < 4; ++f_) {                         \
        _Pragma("unroll") for (int g_ = 0; g_ < 2; ++g_) {                     \
            acc[(MB) + f_][(CB) + g_] = __builtin_amdgcn_mfma_f32_16x16x32_bf16( \
                aF[f_][0], BREG[g_][0], acc[(MB) + f_][(CB) + g_], 0, 0, 0);   \
            acc[(MB) + f_][(CB) + g_] = __builtin_amdgcn_mfma_f32_16x16x32_bf16( \
                aF[f_][1], BREG[g_][1], acc[(MB) + f_][(CB) + g_], 0, 0, 0);   \
        }                                                                      \
    }                                                                          \
    __builtin_amdgcn_s_setprio(0);

template <int OUTMODE>  // 0: bf16 NT out; 1: fp32 out + bias + row guard
__global__ __launch_bounds__(512, 1)
void gemm8ph_kernel(const unsigned short* __restrict__ A, const unsigned short* __restrict__ Bt,
                    unsigned short* __restrict__ obf, float* __restrict__ of32,
                    const float* __restrict__ bias,
                    int K, int lda, int Nld, int nbx, int nmt, int Mrows,
                    long strideA, long strideB, long strideO) {
    __shared__ char smem[131072];
    int tid = threadIdx.x, lane = tid & 63, w = tid >> 6;
    int wm = w >> 2, wn = w & 3;       // 2M x 4N
    int l15 = lane & 15;

    int wg = xcd_remap(blockIdx.x, gridDim.x);
    int bx = wg % nbx; int r1 = wg / nbx; int mt = r1 % nmt; int b = r1 / nmt;
    int m0 = mt << 8, n0 = bx << 8;
    int Mcap = Mrows - m0; if (Mcap > 256) Mcap = 256;
    const char* AgB = (const char*)(A + (long)b * strideA + (size_t)m0 * lda);
    const char* BgB = (const char*)(Bt + (long)b * strideB + (size_t)n0 * K);
    int ldaB = lda << 1, ldbB = K << 1;
    int nkt = K >> 6, niter = nkt >> 1;

    f32x4 zz = {0.f, 0.f, 0.f, 0.f};
    f32x4 acc[8][4];
#pragma unroll
    for (int a = 0; a < 8; ++a)
#pragma unroll
        for (int c = 0; c < 4; ++c) acc[a][c] = zz;

    // prologue: T0 (4 halves) + T1 (A-h0, B-h0, B-h1); vmcnt(6) -> T0 landed, T1x3 in flight
    stA8(AgB, ldaB, Mcap, 0, smem, tid);
    stB8(BgB, ldbB, 0, smem + 32768, tid);
    stB8(BgB, ldbB, 1, smem + 32768 + 16384, tid);
    stA8(AgB, ldaB, Mcap, 1, smem + 16384, tid);
    stA8(AgB + 128, ldaB, Mcap, 0, smem + 65536, tid);
    stB8(BgB + 128, ldbB, 0, smem + 65536 + 32768, tid);
    stB8(BgB + 128, ldbB, 1, smem + 65536 + 32768 + 16384, tid);
    VM6();
    SB(); SCHED0();

    bf16x8 aF[4][2], b0[2][2], b1[2][2];

    for (int i = 0; i < niter; ++i) {
        bool more = (i + 1 < niter);
        long kb1 = ((long)(2 * i + 1)) << 7;   // byte K-offsets
        long kb2 = ((long)(2 * i + 2)) << 7;
        long kb3 = ((long)(2 * i + 3)) << 7;

        // ---- ph1: read A-rh0(buf0)+B-ch0(buf0); stage A-h1(T+1)->buf1 ----
#pragma unroll
        for (int f = 0; f < 4; ++f) { aF[f][0] = rdA8(smem, 0, 0, wm, f, 0, lane);
                                      aF[f][1] = rdA8(smem, 0, 0, wm, f, 1, lane); }
#pragma unroll
        for (int g = 0; g < 2; ++g) { b0[g][0] = rdB8(smem, 0, 0, wn, g, 0, lane);
                                      b0[g][1] = rdB8(smem, 0, 0, wn, g, 1, lane); }
        stA8(AgB + kb1, ldaB, Mcap, 1, smem + 65536 + 16384, tid);
        SB(); LGKM0(); SCHED0();
        CL16(0, 0, b0);
        SB(); SCHED0();
        // ---- ph2: read B-ch1(buf0); stage A-h0(T+2)->buf0 ----
#pragma unroll
        for (int g = 0; g < 2; ++g) { b1[g][0] = rdB8(smem, 0, 1, wn, g, 0, lane);
                                      b1[g][1] = rdB8(smem, 0, 1, wn, g, 1, lane); }
        if (more) stA8(AgB + kb2, ldaB, Mcap, 0, smem, tid);
        SB(); LGKM0(); SCHED0();
        CL16(0, 2, b1);
        SB(); SCHED0();
        // ---- ph3: read A-rh1(buf0); stage B-h0(T+2)->buf0 ----
#pragma unroll
        for (int f = 0; f < 4; ++f) { aF[f][0] = rdA8(smem, 0, 1, wm, f, 0, lane);
                                      aF[f][1] = rdA8(smem, 0, 1, wm, f, 1, lane); }
        if (more) stB8(BgB + kb2, ldbB, 0, smem + 32768, tid);
        SB(); LGKM0(); SCHED0();
        CL16(4, 0, b0);
        SB(); SCHED0();
        // ---- ph4: no reads; stage B-h1(T+2)->buf0; vmcnt ----
        if (more) stB8(BgB + kb2, ldbB, 1, smem + 32768 + 16384, tid);
        SB(); SCHED0();
        CL16(4, 2, b1);
        if (more) { VM6(); } else { VM0(); }
        SB(); SCHED0();

        // ---- ph5: read A-rh0(buf1)+B-ch0(buf1); stage A-h1(T+2)->buf0 ----
#pragma unroll
        for (int f = 0; f < 4; ++f) { aF[f][0] = rdA8(smem, 1, 0, wm, f, 0, lane);
                                      aF[f][1] = rdA8(smem, 1, 0, wm, f, 1, lane); }
#pragma unroll
        for (int g = 0; g < 2; ++g) { b0[g][0] = rdB8(smem, 1, 0, wn, g, 0, lane);
                                      b0[g][1] = rdB8(smem, 1, 0, wn, g, 1, lane); }
        if (more) stA8(AgB + kb2, ldaB, Mcap, 1, smem + 16384, tid);
        SB(); LGKM0(); SCHED0();
        CL16(0, 0, b0);
        SB(); SCHED0();
        // ---- ph6: read B-ch1(buf1); stage A-h0(T+3)->buf1 ----
#pragma unroll
        for (int g = 0; g < 2; ++g) { b1[g][0] = rdB8(smem, 1, 1, wn, g, 0, lane);
                                      b1[g][1] = rdB8(smem, 1, 1, wn, g, 1, lane); }
        if (more) stA8(AgB + kb3, ldaB, Mcap, 0, smem + 65536, tid);
        SB(); LGKM0(); SCHED0();
        CL16(0, 2, b1);
        SB(); SCHED0();
        // ---- ph7: read A-rh1(buf1); stage B-h0(T+3)->buf1 ----
#pragma unroll
        for (int f = 0; f < 4; ++f) { aF[f][0] = rdA8(smem, 1, 1, wm, f, 0, lane);
                                      aF[f][1] = rdA8(smem, 1, 1, wm, f, 1, lane); }
        if (more) stB8(BgB + kb3, ldbB, 0, smem + 65536 + 32768, tid);
        SB(); LGKM0(); SCHED0();
        CL16(4, 0, b0);
        SB(); SCHED0();
        // ---- ph8: no reads; stage B-h1(T+3)->buf1; vmcnt ----
        if (more) stB8(BgB + kb3, ldbB, 1, smem + 65536 + 32768 + 16384, tid);
        SB(); SCHED0();
        CL16(4, 2, b1);
        if (more) VM6();
        SB(); SCHED0();
    }

    int rbase = m0 + (wm << 7) + ((lane >> 4) << 2);
    int cbase = n0 + (wn << 6) + l15;
    if (OUTMODE == 0) {
#pragma unroll
        for (int fm = 0; fm < 8; ++fm)
#pragma unroll
            for (int j = 0; j < 4; ++j) {
                size_t ro = (size_t)(rbase + (fm << 4) + j) * Nld;
#pragma unroll
                for (int fn = 0; fn < 4; ++fn)
                    __builtin_nontemporal_store(f2bf(acc[fm][fn][j]), &obf[ro + cbase + (fn << 4)]);
            }
    } else {
        float bv[4];
#pragma unroll
        for (int fn = 0; fn < 4; ++fn) bv[fn] = bias[cbase + (fn << 4)];
#pragma unroll
        for (int fm = 0; fm < 8; ++fm)
#pragma unroll
            for (int j = 0; j < 4; ++j) {
                int rr = rbase + (fm << 4) + j;
                if (rr < Mrows) {
                    size_t ro = (long)b * strideO + (size_t)rr * Nld;
#pragma unroll
                    for (int fn = 0; fn < 4; ++fn)
                        of32[ro + cbase + (fn << 4)] = acc[fm][fn][j] + bv[fn];
                }
            }
    }
}

// ---------------- covariance via MFMA (R13-proven: LDS transpose, atomics, no prefetch) ----------
__global__ __launch_bounds__(256)
void cov_mfma_kernel(const unsigned short* __restrict__ qkv, float* __restrict__ S,
                     float* __restrict__ qn2, float* __restrict__ kn2) {
    __shared__ unsigned short Kl[96 * 40];
    __shared__ unsigned short Ql[96 * 40];
    int bh = blockIdx.x;
    int b = bh >> 3, h = bh & 7;
    int tok0 = blockIdx.y * 448;
    int tid = threadIdx.x;
    int lane = tid & 63, w = tid >> 6;
    int wr = w & 1, wc = w >> 1;
    int rot = tid & 7;

    f32x4 zz = {0.f, 0.f, 0.f, 0.f};
    f32x4 acc[3][3];
#pragma unroll
    for (int a = 0; a < 3; ++a)
#pragma unroll
        for (int c = 0; c < 3; ++c) acc[a][c] = zz;
    float qn = 0.f, kn = 0.f;

    const uint4* qg = (const uint4*)qkv;

    for (int step = 0; step < 14; ++step) {
        int tokBase = b * 3136 + tok0 + (step << 5);
        __syncthreads();
#pragma unroll
        for (int r = 0; r < 3; ++r) {
            int idx = (r << 8) + tid;
            int isK = idx >= 384;
            int j = isK ? idx - 384 : idx;
            int tok = j / 12, c = j % 12;
            uint4 u = qg[(size_t)(tokBase + tok) * 288 + h * 12 + (isK ? 96 : 0) + c];
            unsigned short* dst = isK ? Kl : Ql;
            const unsigned short* us = (const unsigned short*)&u;
#pragma unroll
            for (int i = 0; i < 8; ++i) {
                int e = (i + rot) & 7;
                dst[(c * 8 + e) * 40 + tok] = us[e];
            }
        }
        __syncthreads();
        if (tid < 96) {
#pragma unroll
            for (int t = 0; t < 4; ++t) {
                bf16x8 v = *(const bf16x8*)((const char*)Ql + tid * 80 + (t << 4));
#pragma unroll
                for (int i = 0; i < 8; ++i) { float f = (float)v[i]; qn = fmaf(f, f, qn); }
            }
        } else if (tid >= 128 && tid < 224) {
            int c = tid - 128;
#pragma unroll
            for (int t = 0; t < 4; ++t) {
                bf16x8 v = *(const bf16x8*)((const char*)Kl + c * 80 + (t << 4));
#pragma unroll
                for (int i = 0; i < 8; ++i) { float f = (float)v[i]; kn = fmaf(f, f, kn); }
            }
        }
        int kbyte = (lane >> 4) << 4;
        bf16x8 af[3], bfv[3];
#pragma unroll
        for (int f = 0; f < 3; ++f)
            af[f] = *(const bf16x8*)((const char*)Kl + (wr * 48 + f * 16 + (lane & 15)) * 80 + kbyte);
#pragma unroll
        for (int f = 0; f < 3; ++f)
            bfv[f] = *(const bf16x8*)((const char*)Ql + (wc * 48 + f * 16 + (lane & 15)) * 80 + kbyte);
#pragma unroll
        for (int fm = 0; fm < 3; ++fm)
#pragma unroll
            for (int fn = 0; fn < 3; ++fn)
                acc[fm][fn] = __builtin_amdgcn_mfma_f32_16x16x32_bf16(af[fm], bfv[fn], acc[fm][fn], 0, 0, 0);
    }

    float* Sb = S + (size_t)bh * 9216;
    int rloc = wr * 48 + ((lane >> 4) << 2);
    int cloc = wc * 48 + (lane & 15);
#pragma unroll
    for (int fm = 0; fm < 3; ++fm)
#pragma unroll
        for (int fn = 0; fn < 3; ++fn)
#pragma unroll
            for (int j = 0; j < 4; ++j)
                atomicAdd(&Sb[(rloc + fm * 16 + j) * 96 + cloc + fn * 16], acc[fm][fn][j]);
    if (tid < 96) atomicAdd(&qn2[bh * 96 + tid], qn);
    if (tid >= 128 && tid < 224) atomicAdd(&kn2[bh * 96 + tid - 128], kn);
}

// ------- merged softmax + M precompute, 512 blocks (4 per bh, redundant softmax) -------
__global__ __launch_bounds__(256)
void softmax_M_kernel(const float* __restrict__ S, const float* __restrict__ qn2,
                      const float* __restrict__ kn2, const float* __restrict__ temp,
                      const unsigned short* __restrict__ wprojt, unsigned short* __restrict__ MT) {
    int bh = blockIdx.x >> 2, oc = blockIdx.x & 3;
    int h = bh & 7, b = bh >> 3;
    __shared__ float Sl[96 * 97];
    __shared__ float qinv[96];
    __shared__ unsigned short At[96 * 96];
    int tid = threadIdx.x, lane = tid & 63, w = tid >> 6;
    int l15 = lane & 15;
    const float* Sg = S + (size_t)bh * 9216;
    for (int i = tid; i < 9216; i += 256) Sl[(i / 96) * 97 + (i % 96)] = Sg[i];
    if (tid < 96) qinv[tid] = 1.f / fmaxf(sqrtf(qn2[bh * 96 + tid]), 1e-12f);
    __syncthreads();
    if (tid < 96) {
        int c = tid;
        float scale = (1.f / fmaxf(sqrtf(kn2[bh * 96 + c]), 1e-12f)) * temp[h];
        float* row = &Sl[c * 97];
        float mx = -3.4e38f;
        for (int e = 0; e < 96; ++e) {
            float v = row[e] * scale * qinv[e];
            row[e] = v;
            mx = fmaxf(mx, v);
        }
        float s = 0.f;
        for (int e = 0; e < 96; ++e) {
            float p = __expf(row[e] - mx);
            row[e] = p;
            s += p;
        }
        float inv = 1.f / s;
        for (int e = 0; e < 96; ++e) At[e * 96 + c] = f2bf(row[e] * inv);
    }
    __syncthreads();

    int o0 = oc * 192 + w * 48;
    f32x4 zz = {0.f, 0.f, 0.f, 0.f};
    f32x4 acc[6][3];
#pragma unroll
    for (int f = 0; f < 6; ++f)
#pragma unroll
        for (int g = 0; g < 3; ++g) acc[f][g] = zz;
#pragma unroll
    for (int ks = 0; ks < 3; ++ks) {
        int koff = ks * 32 + ((lane >> 4) << 3);
        bf16x8 a[6], bb[3];
#pragma unroll
        for (int f = 0; f < 6; ++f)
            a[f] = *(const bf16x8*)(At + (f * 16 + l15) * 96 + koff);
#pragma unroll
        for (int g = 0; g < 3; ++g)
            bb[g] = *(const bf16x8*)(wprojt + (size_t)(o0 + g * 16 + l15) * 768 + h * 96 + koff);
#pragma unroll
        for (int f = 0; f < 6; ++f)
#pragma unroll
            for (int g = 0; g < 3; ++g)
                acc[f][g] = __builtin_amdgcn_mfma_f32_16x16x32_bf16(a[f], bb[g], acc[f][g], 0, 0, 0);
    }
#pragma unroll
    for (int f = 0; f < 6; ++f)
#pragma unroll
        for (int g = 0; g < 3; ++g) {
            int e = f * 16 + ((lane >> 4) << 2);
            int o = o0 + g * 16 + l15;
            ushort4 pk;
            pk.x = f2bf(acc[f][g][0]); pk.y = f2bf(acc[f][g][1]);
            pk.z = f2bf(acc[f][g][2]); pk.w = f2bf(acc[f][g][3]);
            *(ushort4*)&MT[((size_t)b * 768 + o) * 768 + h * 96 + e] = pk;
        }
}

// ---------------- launch ----------------
extern "C" void kernel_launch(void* const* d_in, const int* in_sizes, int n_in,
                              void* d_out, int out_size, void* d_ws, size_t ws_size,
                              hipStream_t stream) {
    const float* x     = (const float*)d_in[0];
    const float* Wqkv  = (const float*)d_in[1];
    const float* temp  = (const float*)d_in[2];
    const float* Wproj = (const float*)d_in[3];
    const float* bproj = (const float*)d_in[4];
    float* out = (float*)d_out;
    char* ws = (char*)d_ws;

    unsigned short* xbf    = (unsigned short*)(ws);                 //  77,070,336
    unsigned short* qkvbf  = (unsigned short*)(ws + 77070336);      // 231,211,008
    unsigned short* wqkvt  = (unsigned short*)(ws + 308281344);     //   3,538,944
    unsigned short* wprojt = (unsigned short*)(ws + 311820288);     //   1,179,648
    float*          Sbuf   = (float*)        (ws + 312999936);      //   4,718,592
    float*          qn2    = (float*)        (ws + 317718528);      //      49,152
    float*          kn2    = (float*)        (ws + 317767680);      //      49,152
    unsigned short* MT     = xbf;  // alias: x_bf16 dead after GEMM1

    // fused prep: Wqkv^T | Wproj^T | x cvt | zero Sbuf/qn2/kn2
    prep_kernel<<<4646, 256, 0, stream>>>(x, (ushort4*)xbf, Wqkv, wqkvt, Wproj, wprojt,
                                          (float4*)Sbuf);

    // qkv = x @ Wqkv  [50176 x 2304]: 196 x 9 tiles of 256^2, 8-phase pipelined
    gemm8ph_kernel<0><<<196 * 9, 512, 0, stream>>>(xbf, wqkvt, qkvbf, nullptr, nullptr,
                                                   768, 768, 2304, 9, 196, 50176, 0, 0, 0);
    // S = K^T Q (per bh), + channel norms
    cov_mfma_kernel<<<dim3(128, 7), 256, 0, stream>>>(qkvbf, Sbuf, qn2, kn2);
    // softmax + MT precompute (merged, 4 blocks/bh)
    softmax_M_kernel<<<512, 256, 0, stream>>>(Sbuf, qn2, kn2, temp, wprojt, MT);
    // out[b] = qkvV_b @ MT_b^T + bias : 16 b x 13 x 3 tiles of 256^2
    gemm8ph_kernel<1><<<16 * 13 * 3, 512, 0, stream>>>(qkvbf + 1536, MT, nullptr, out, bproj,
                                                       768, 2304, 768, 3, 13, 3136,
                                                       7225344L, 589824L, 2408448L);
}

// Round 17
// 383.623 us; speedup vs baseline: 1.0446x; 1.0446x over previous
//
#include <hip/hip_runtime.h>

using bf16x8 = __attribute__((ext_vector_type(8))) __bf16;
using f32x4  = __attribute__((ext_vector_type(4))) float;

#define AS1 __attribute__((address_space(1)))
#define AS3 __attribute__((address_space(3)))

__device__ __forceinline__ unsigned short f2bf(float f) {
    unsigned int x = __float_as_uint(f);
    x += 0x7fffu + ((x >> 16) & 1u);   // RNE
    return (unsigned short)(x >> 16);
}

// bijective XCD-aware block remap (m204)
__device__ __forceinline__ int xcd_remap(int orig, int nwg) {
    int q = nwg >> 3, r = nwg & 7;
    int xcd = orig & 7, lin = orig >> 3;
    return (xcd < r ? xcd * (q + 1) : r * (q + 1) + (xcd - r) * q) + lin;
}

// ---- fused prep: Wqkv^T (1728) | Wproj^T (576) | x cvt (2048) | zero S/qn2/kn2 (294) ----
__global__ __launch_bounds__(256)
void prep_kernel(const float* __restrict__ x, ushort4* __restrict__ xbf,
                 const float* __restrict__ Wqkv, unsigned short* __restrict__ wqkvt,
                 const float* __restrict__ Wproj, unsigned short* __restrict__ wprojt,
                 float4* __restrict__ zbase) {
    __shared__ float tile[32][33];
    int bid = blockIdx.x, tid = threadIdx.x;
    if (bid < 2304) {
        const float* W; unsigned short* Wt; int K = 768, N; int bx, by;
        if (bid < 1728) { W = Wqkv; Wt = wqkvt; N = 2304; bx = bid % 72; by = bid / 72; }
        else            { int t = bid - 1728; W = Wproj; Wt = wprojt; N = 768; bx = t % 24; by = t / 24; }
        int n0 = bx << 5, k0 = by << 5;
        int tx = tid & 31, ty = tid >> 5;      // 32 x 8
#pragma unroll
        for (int i = 0; i < 32; i += 8)
            tile[ty + i][tx] = W[(size_t)(k0 + ty + i) * N + (n0 + tx)];
        __syncthreads();
#pragma unroll
        for (int i = 0; i < 32; i += 8)
            Wt[(size_t)(n0 + ty + i) * K + (k0 + tx)] = f2bf(tile[tx][ty + i]);
    } else if (bid < 4352) {
        int vb = bid - 2304;
        const float4* in = (const float4*)x;
        int n4 = 38535168 / 4;
        int stride = 2048 * 256;
        for (int i = vb * 256 + tid; i < n4; i += stride) {
            float4 v = in[i];
            ushort4 o;
            o.x = f2bf(v.x); o.y = f2bf(v.y); o.z = f2bf(v.z); o.w = f2bf(v.w);
            xbf[i] = o;
        }
    } else {
        // zero Sbuf+qn2+kn2: 301056 float4s over 294 blocks
        int z = bid - 4352;
        float4 zz4 = {0.f, 0.f, 0.f, 0.f};
        for (int i = z * 256 + tid; i < 301056; i += 294 * 256) zbase[i] = zz4;
    }
}

// ================ proven m97-structure GEMM + XCD remap + NT C-store ================
__device__ __forceinline__ void stage_tile_128x64(const unsigned short* g, int ldK,
                                                  unsigned short* lds, int tid) {
#pragma unroll
    for (int r = 0; r < 4; ++r) {
        int i = (r << 8) + tid;              // 0..1023 : 16B chunks
        int row = i >> 3;
        int colb = (i & 7) << 4;
        int srcb = row * (ldK << 1) + (colb ^ ((row & 7) << 4));
        __builtin_amdgcn_global_load_lds(
            (AS1 unsigned int*)(unsigned long long)((const char*)g + srcb),
            (AS3 unsigned int*)((char*)lds + (i << 4)),
            16, 0, 0);
    }
}

__device__ __forceinline__ bf16x8 lds_read_swz(const unsigned short* base, int row, int kbyte) {
    int off = (row << 7) + (kbyte ^ ((row & 7) << 4));
    return *(const bf16x8*)((const char*)base + off);
}

__global__ __launch_bounds__(256, 2)
void gemm_bt_kernel(const unsigned short* __restrict__ A, const unsigned short* __restrict__ Bt,
                    unsigned short* __restrict__ obf, int M, int N, int K, int ntx) {
    __shared__ unsigned short As[128 * 64];
    __shared__ unsigned short Bs[128 * 64];
    int tid = threadIdx.x;
    int lane = tid & 63, w = tid >> 6;
    int wm = w >> 1, wn = w & 1;
    int wg = xcd_remap(blockIdx.x, gridDim.x);
    int bx = wg % ntx, by = wg / ntx;
    int m0 = by << 7, n0 = bx << 7;
    const unsigned short* Ag = A + (size_t)m0 * K;
    const unsigned short* Bg = Bt + (size_t)n0 * K;

    f32x4 zz = {0.f, 0.f, 0.f, 0.f};
    f32x4 acc[4][4];
#pragma unroll
    for (int a = 0; a < 4; ++a)
#pragma unroll
        for (int b = 0; b < 4; ++b) acc[a][b] = zz;

    for (int kb = 0; kb < K; kb += 64) {
        stage_tile_128x64(Ag + kb, K, As, tid);
        stage_tile_128x64(Bg + kb, K, Bs, tid);
        __syncthreads();
#pragma unroll
        for (int ks = 0; ks < 2; ++ks) {
            int kbyte = (ks << 6) + ((lane >> 4) << 4);
            bf16x8 af[4], bfr[4];
#pragma unroll
            for (int f = 0; f < 4; ++f)
                af[f] = lds_read_swz(As, (wm << 6) + (f << 4) + (lane & 15), kbyte);
#pragma unroll
            for (int f = 0; f < 4; ++f)
                bfr[f] = lds_read_swz(Bs, (wn << 6) + (f << 4) + (lane & 15), kbyte);
#pragma unroll
            for (int fm = 0; fm < 4; ++fm)
#pragma unroll
                for (int fn = 0; fn < 4; ++fn)
                    acc[fm][fn] = __builtin_amdgcn_mfma_f32_16x16x32_bf16(af[fm], bfr[fn], acc[fm][fn], 0, 0, 0);
        }
        __syncthreads();
    }

    int rbase = m0 + (wm << 6) + ((lane >> 4) << 2);
    int cbase = n0 + (wn << 6) + (lane & 15);
#pragma unroll
    for (int fm = 0; fm < 4; ++fm)
#pragma unroll
        for (int j = 0; j < 4; ++j) {
            size_t ro = (size_t)(rbase + (fm << 4) + j) * N;
#pragma unroll
            for (int fn = 0; fn < 4; ++fn)
                __builtin_nontemporal_store(f2bf(acc[fm][fn][j]), &obf[ro + cbase + (fn << 4)]);
        }
}

// ================ fused V@M projection GEMM: out[b] = qkvV_b[3136,768] @ MT_b^T + bias ==========
__global__ __launch_bounds__(256, 2)
void gemm_v_proj_kernel(const unsigned short* __restrict__ qkv, const unsigned short* __restrict__ MT,
                        float* __restrict__ out, const float* __restrict__ bias) {
    __shared__ unsigned short As[128 * 64];
    __shared__ unsigned short Bs[128 * 64];
    int tid = threadIdx.x;
    int lane = tid & 63, w = tid >> 6;
    int wm = w >> 1, wn = w & 1;
    int wg = xcd_remap(blockIdx.x, gridDim.x);   // nwg = 16*25*6 = 2400
    int bx = wg % 6;
    int t2 = wg / 6;
    int mt = t2 % 25, b = t2 / 25;
    int m0 = mt << 7, n0 = bx << 7;
    const unsigned short* Ab = qkv + (size_t)b * 3136 * 2304 + 1536;   // V block (ushort units)
    const unsigned short* Bg = MT + (size_t)b * 589824 + (size_t)n0 * 768;

    f32x4 zz = {0.f, 0.f, 0.f, 0.f};
    f32x4 acc[4][4];
#pragma unroll
    for (int a = 0; a < 4; ++a)
#pragma unroll
        for (int c = 0; c < 4; ++c) acc[a][c] = zz;

    for (int kb = 0; kb < 768; kb += 64) {
#pragma unroll
        for (int r = 0; r < 4; ++r) {
            int i = (r << 8) + tid;
            int row = i >> 3, slot = i & 7;
            int rg = m0 + row; if (rg > 3135) rg = 3135;
            const char* src = (const char*)(Ab + (size_t)rg * 2304 + kb) + ((slot ^ (row & 7)) << 4);
            __builtin_amdgcn_global_load_lds(
                (AS1 unsigned int*)(unsigned long long)src,
                (AS3 unsigned int*)((char*)As + (i << 4)), 16, 0, 0);
        }
        stage_tile_128x64(Bg + kb, 768, Bs, tid);
        __syncthreads();
#pragma unroll
        for (int ks = 0; ks < 2; ++ks) {
            int kbyte = (ks << 6) + ((lane >> 4) << 4);
            bf16x8 af[4], bfr[4];
#pragma unroll
            for (int f = 0; f < 4; ++f)
                af[f] = lds_read_swz(As, (wm << 6) + (f << 4) + (lane & 15), kbyte);
#pragma unroll
            for (int f = 0; f < 4; ++f)
                bfr[f] = lds_read_swz(Bs, (wn << 6) + (f << 4) + (lane & 15), kbyte);
#pragma unroll
            for (int fm = 0; fm < 4; ++fm)
#pragma unroll
                for (int fn = 0; fn < 4; ++fn)
                    acc[fm][fn] = __builtin_amdgcn_mfma_f32_16x16x32_bf16(af[fm], bfr[fn], acc[fm][fn], 0, 0, 0);
        }
        __syncthreads();
    }

    int rloc = m0 + (wm << 6) + ((lane >> 4) << 2);
    int cbase = n0 + (wn << 6) + (lane & 15);
    float bv[4];
#pragma unroll
    for (int fn = 0; fn < 4; ++fn) bv[fn] = bias[cbase + (fn << 4)];
#pragma unroll
    for (int fm = 0; fm < 4; ++fm)
#pragma unroll
        for (int j = 0; j < 4; ++j) {
            int rr = rloc + (fm << 4) + j;
            if (rr < 3136) {
                size_t ro = ((size_t)b * 3136 + rr) * 768;
#pragma unroll
                for (int fn = 0; fn < 4; ++fn)
                    out[ro + cbase + (fn << 4)] = acc[fm][fn][j] + bv[fn];
            }
        }
}

// ---------------- covariance via MFMA (R13-proven: LDS transpose, atomics, no prefetch) ----------
__global__ __launch_bounds__(256)
void cov_mfma_kernel(const unsigned short* __restrict__ qkv, float* __restrict__ S,
                     float* __restrict__ qn2, float* __restrict__ kn2) {
    __shared__ unsigned short Kl[96 * 40];   // [channel][token], stride 40 ushorts (80B)
    __shared__ unsigned short Ql[96 * 40];
    int bh = blockIdx.x;
    int b = bh >> 3, h = bh & 7;
    int tok0 = blockIdx.y * 448;
    int tid = threadIdx.x;
    int lane = tid & 63, w = tid >> 6;
    int wr = w & 1, wc = w >> 1;
    int rot = tid & 7;

    f32x4 zz = {0.f, 0.f, 0.f, 0.f};
    f32x4 acc[3][3];
#pragma unroll
    for (int a = 0; a < 3; ++a)
#pragma unroll
        for (int c = 0; c < 3; ++c) acc[a][c] = zz;
    float qn = 0.f, kn = 0.f;

    const uint4* qg = (const uint4*)qkv;   // qkv row = 288 uint4

    for (int step = 0; step < 14; ++step) {
        int tokBase = b * 3136 + tok0 + (step << 5);
        __syncthreads();
#pragma unroll
        for (int r = 0; r < 3; ++r) {
            int idx = (r << 8) + tid;          // 0..767 ; 0..383 = Q, 384..767 = K
            int isK = idx >= 384;
            int j = isK ? idx - 384 : idx;
            int tok = j / 12, c = j % 12;
            uint4 u = qg[(size_t)(tokBase + tok) * 288 + h * 12 + (isK ? 96 : 0) + c];
            unsigned short* dst = isK ? Kl : Ql;
            const unsigned short* us = (const unsigned short*)&u;
#pragma unroll
            for (int i = 0; i < 8; ++i) {
                int e = (i + rot) & 7;
                dst[(c * 8 + e) * 40 + tok] = us[e];
            }
        }
        __syncthreads();
        if (tid < 96) {
#pragma unroll
            for (int t = 0; t < 4; ++t) {
                bf16x8 v = *(const bf16x8*)((const char*)Ql + tid * 80 + (t << 4));
#pragma unroll
                for (int i = 0; i < 8; ++i) { float f = (float)v[i]; qn = fmaf(f, f, qn); }
            }
        } else if (tid >= 128 && tid < 224) {
            int c = tid - 128;
#pragma unroll
            for (int t = 0; t < 4; ++t) {
                bf16x8 v = *(const bf16x8*)((const char*)Kl + c * 80 + (t << 4));
#pragma unroll
                for (int i = 0; i < 8; ++i) { float f = (float)v[i]; kn = fmaf(f, f, kn); }
            }
        }
        int kbyte = (lane >> 4) << 4;
        bf16x8 af[3], bfv[3];
#pragma unroll
        for (int f = 0; f < 3; ++f)
            af[f] = *(const bf16x8*)((const char*)Kl + (wr * 48 + f * 16 + (lane & 15)) * 80 + kbyte);
#pragma unroll
        for (int f = 0; f < 3; ++f)
            bfv[f] = *(const bf16x8*)((const char*)Ql + (wc * 48 + f * 16 + (lane & 15)) * 80 + kbyte);
#pragma unroll
        for (int fm = 0; fm < 3; ++fm)
#pragma unroll
            for (int fn = 0; fn < 3; ++fn)
                acc[fm][fn] = __builtin_amdgcn_mfma_f32_16x16x32_bf16(af[fm], bfv[fn], acc[fm][fn], 0, 0, 0);
    }

    float* Sb = S + (size_t)bh * 9216;
    int rloc = wr * 48 + ((lane >> 4) << 2);
    int cloc = wc * 48 + (lane & 15);
#pragma unroll
    for (int fm = 0; fm < 3; ++fm)
#pragma unroll
        for (int fn = 0; fn < 3; ++fn)
#pragma unroll
            for (int j = 0; j < 4; ++j)
                atomicAdd(&Sb[(rloc + fm * 16 + j) * 96 + cloc + fn * 16], acc[fm][fn][j]);
    if (tid < 96) atomicAdd(&qn2[bh * 96 + tid], qn);
    if (tid >= 128 && tid < 224) atomicAdd(&kn2[bh * 96 + tid - 128], kn);
}

// ------- merged softmax + M precompute, 512 blocks (4 per bh, redundant softmax) -------
__global__ __launch_bounds__(256)
void softmax_M_kernel(const float* __restrict__ S, const float* __restrict__ qn2,
                      const float* __restrict__ kn2, const float* __restrict__ temp,
                      const unsigned short* __restrict__ wprojt, unsigned short* __restrict__ MT) {
    int bh = blockIdx.x >> 2, oc = blockIdx.x & 3;
    int h = bh & 7, b = bh >> 3;
    __shared__ float Sl[96 * 97];
    __shared__ float qinv[96];
    __shared__ unsigned short At[96 * 96];   // attnT[e][c] bf16
    int tid = threadIdx.x, lane = tid & 63, w = tid >> 6;
    int l15 = lane & 15;
    const float* Sg = S + (size_t)bh * 9216;
    for (int i = tid; i < 9216; i += 256) Sl[(i / 96) * 97 + (i % 96)] = Sg[i];
    if (tid < 96) qinv[tid] = 1.f / fmaxf(sqrtf(qn2[bh * 96 + tid]), 1e-12f);
    __syncthreads();
    if (tid < 96) {
        int c = tid;
        float scale = (1.f / fmaxf(sqrtf(kn2[bh * 96 + c]), 1e-12f)) * temp[h];
        float* row = &Sl[c * 97];
        float mx = -3.4e38f;
        for (int e = 0; e < 96; ++e) {
            float v = row[e] * scale * qinv[e];
            row[e] = v;
            mx = fmaxf(mx, v);
        }
        float s = 0.f;
        for (int e = 0; e < 96; ++e) {
            float p = __expf(row[e] - mx);
            row[e] = p;
            s += p;
        }
        float inv = 1.f / s;
        for (int e = 0; e < 96; ++e) At[e * 96 + c] = f2bf(row[e] * inv);
    }
    __syncthreads();

    int o0 = oc * 192 + w * 48;
    f32x4 zz = {0.f, 0.f, 0.f, 0.f};
    f32x4 acc[6][3];
#pragma unroll
    for (int f = 0; f < 6; ++f)
#pragma unroll
        for (int g = 0; g < 3; ++g) acc[f][g] = zz;
#pragma unroll
    for (int ks = 0; ks < 3; ++ks) {
        int koff = ks * 32 + ((lane >> 4) << 3);
        bf16x8 a[6], bb[3];
#pragma unroll
        for (int f = 0; f < 6; ++f)
            a[f] = *(const bf16x8*)(At + (f * 16 + l15) * 96 + koff);
#pragma unroll
        for (int g = 0; g < 3; ++g)
            bb[g] = *(const bf16x8*)(wprojt + (size_t)(o0 + g * 16 + l15) * 768 + h * 96 + koff);
#pragma unroll
        for (int f = 0; f < 6; ++f)
#pragma unroll
            for (int g = 0; g < 3; ++g)
                acc[f][g] = __builtin_amdgcn_mfma_f32_16x16x32_bf16(a[f], bb[g], acc[f][g], 0, 0, 0);
    }
#pragma unroll
    for (int f = 0; f < 6; ++f)
#pragma unroll
        for (int g = 0; g < 3; ++g) {
            int e = f * 16 + ((lane >> 4) << 2);
            int o = o0 + g * 16 + l15;
            ushort4 pk;
            pk.x = f2bf(acc[f][g][0]); pk.y = f2bf(acc[f][g][1]);
            pk.z = f2bf(acc[f][g][2]); pk.w = f2bf(acc[f][g][3]);
            *(ushort4*)&MT[((size_t)b * 768 + o) * 768 + h * 96 + e] = pk;
        }
}

// ---------------- launch ----------------
extern "C" void kernel_launch(void* const* d_in, const int* in_sizes, int n_in,
                              void* d_out, int out_size, void* d_ws, size_t ws_size,
                              hipStream_t stream) {
    const float* x     = (const float*)d_in[0];
    const float* Wqkv  = (const float*)d_in[1];
    const float* temp  = (const float*)d_in[2];
    const float* Wproj = (const float*)d_in[3];
    const float* bproj = (const float*)d_in[4];
    float* out = (float*)d_out;
    char* ws = (char*)d_ws;

    unsigned short* xbf    = (unsigned short*)(ws);                 //  77,070,336
    unsigned short* qkvbf  = (unsigned short*)(ws + 77070336);      // 231,211,008
    unsigned short* wqkvt  = (unsigned short*)(ws + 308281344);     //   3,538,944
    unsigned short* wprojt = (unsigned short*)(ws + 311820288);     //   1,179,648
    float*          Sbuf   = (float*)        (ws + 312999936);      //   4,718,592
    float*          qn2    = (float*)        (ws + 317718528);      //      49,152
    float*          kn2    = (float*)        (ws + 317767680);      //      49,152
    unsigned short* MT     = xbf;  // alias: x_bf16 dead after GEMM1

    // fused prep: Wqkv^T | Wproj^T | x cvt | zero Sbuf/qn2/kn2
    prep_kernel<<<4646, 256, 0, stream>>>(x, (ushort4*)xbf, Wqkv, wqkvt, Wproj, wprojt,
                                          (float4*)Sbuf);

    // qkv = x @ Wqkv  [50176 x 2304]: 392x18 tiles of 128^2, XCD-remapped 1D grid
    gemm_bt_kernel<<<392 * 18, 256, 0, stream>>>(xbf, wqkvt, qkvbf, 50176, 2304, 768, 18);
    // S = K^T Q (per bh), + channel norms
    cov_mfma_kernel<<<dim3(128, 7), 256, 0, stream>>>(qkvbf, Sbuf, qn2, kn2);
    // softmax + MT precompute (merged, 4 blocks/bh)
    softmax_M_kernel<<<512, 256, 0, stream>>>(Sbuf, qn2, kn2, temp, wprojt, MT);
    // out[b] = qkvV_b @ MT_b^T + bias
    gemm_v_proj_kernel<<<2400, 256, 0, stream>>>(qkvbf, MT, out, bproj);
}